// Round 15
// baseline (2826.659 us; speedup 1.0000x reference)
//
#include <hip/hip_runtime.h>
#include <math.h>

#define B_    32
#define N_    256
#define DIN   512
#define DOUT  2048
#define RANK_ 12
#define K_    16
#define HC    192
#define CD    1536
#define P1    192
#define P2    384

typedef short short8 __attribute__((ext_vector_type(8)));
typedef float f32x4 __attribute__((ext_vector_type(4)));

__device__ inline short bf16r(float f) {
  unsigned u = __float_as_uint(f);
  unsigned r = (u + 0x7FFFu + ((u >> 16) & 1u)) >> 16;
  return (short)r;
}
__device__ inline float b16f(short s) {
  unsigned u = ((unsigned)(unsigned short)s) << 16;
  return __uint_as_float(u);
}

// ---------------- pre1: stats partials (0..255) || copy_bases (256..2175) ----------------
__global__ __launch_bounds__(256) void k_pre1(const float* __restrict__ x,
                                              const float* __restrict__ leftb,
                                              const float* __restrict__ rightb,
                                              float* __restrict__ sp, float* __restrict__ s2p,
                                              float* __restrict__ Lcat, float* __restrict__ E) {
  int bx = blockIdx.x, t = threadIdx.x;
  if (bx < 256) {
    int b = bx >> 3, c = bx & 7;
    const float* xb = x + (size_t)b * N_ * DIN;
#pragma unroll
    for (int h2 = 0; h2 < 2; ++h2) {
      int d = t + h2 * 256;
      float s = 0.f, s2 = 0.f;
      for (int n = c * 32; n < c * 32 + 32; ++n) {
        float v = xb[(size_t)n * DIN + d];
        s += v; s2 += v * v;
      }
      sp[(size_t)(b * 8 + c) * DIN + d] = s;
      s2p[(size_t)(b * 8 + c) * DIN + d] = s2;
    }
  } else {
    int idx = (bx - 256) * 256 + t;
    const int totL = DOUT * P1;
    const int totR = DIN * P1;
    if (idx < totL) {
      int m = idx / P1, j = idx - m * P1;
      int k = j / RANK_, r = j - k * RANK_;
      Lcat[idx] = leftb[((size_t)k * DOUT + m) * RANK_ + r];
    } else if (idx < totL + totR) {
      int i2 = idx - totL;
      int d = i2 / P1, j = i2 - d * P1;
      int k = j / RANK_, r = j - k * RANK_;
      E[(size_t)d * P2 + j] = rightb[((size_t)k * DIN + d) * RANK_ + r];
    }
  }
}

// ---------------- shared TN GEMM body with K-range ----------------
__device__ inline void gemm_tn_part(const float* __restrict__ A, const float* __restrict__ B,
                                    float* __restrict__ C, int i0, int j0, int kb0, int klen,
                                    int lda, int ldb, int ldc,
                                    float (*As)[33], float (*Bs)[33], int t) {
  int ii = t & 31, j4 = (t >> 5) * 4;
  float acc[4] = {0.f, 0.f, 0.f, 0.f};
  for (int kb = kb0; kb < kb0 + klen; kb += 32) {
    for (int idx = t; idx < 1024; idx += 256) {
      int kk = idx >> 5, c = idx & 31;
      As[kk][c] = A[(size_t)(kb + kk) * lda + i0 + c];
      Bs[kk][c] = B[(size_t)(kb + kk) * ldb + j0 + c];
    }
    __syncthreads();
#pragma unroll 8
    for (int kk = 0; kk < 32; ++kk) {
      float a = As[kk][ii];
#pragma unroll
      for (int q = 0; q < 4; ++q) acc[q] = fmaf(a, Bs[kk][j4 + q], acc[q]);
    }
    __syncthreads();
  }
#pragma unroll
  for (int q = 0; q < 4; ++q) C[(size_t)(i0 + ii) * ldc + j0 + j4 + q] = acc[q];
}

// ---------------- pre2: h-GEMM (0..95) || Pcat splitK (96..479) || GLL splitK (480..623) ----
__global__ __launch_bounds__(256) void k_pre2(const float* __restrict__ x,
                                              const float* __restrict__ sp, const float* __restrict__ s2p,
                                              const float* __restrict__ W1, const float* __restrict__ b1,
                                              const float* __restrict__ U0, const float* __restrict__ LcatF,
                                              float* __restrict__ hgel,
                                              float* __restrict__ Ppart, float* __restrict__ GLLpart) {
  int bx = blockIdx.x, t = threadIdx.x;
  __shared__ float As[32][33], Bs[32][33];
  __shared__ float zsh[CD];
  __shared__ float hp[4][64];
  if (bx < 96) {
    int b = bx / 3, jt = bx % 3;
    int j0 = jt * 64;
    for (int d = t; d < CD; d += 256) {
      float v;
      if (d < DIN) {
        v = x[(size_t)b * N_ * DIN + d];
      } else {
        int dd = d & 511;
        float s = 0.f;
#pragma unroll
        for (int c2 = 0; c2 < 8; ++c2) s += sp[(size_t)(b * 8 + c2) * DIN + dd];
        float mean = s * (1.0f / N_);
        if (d < 2 * DIN) v = mean;
        else {
          float s2 = 0.f;
#pragma unroll
          for (int c2 = 0; c2 < 8; ++c2) s2 += s2p[(size_t)(b * 8 + c2) * DIN + dd];
          v = s2 * (1.0f / N_) - mean * mean;
        }
      }
      zsh[d] = v;
    }
    __syncthreads();
    int j = t & 63, kg = t >> 6;
    float a = 0.f;
    for (int d = kg * 384; d < kg * 384 + 384; ++d)
      a = fmaf(zsh[d], W1[(size_t)d * HC + j0 + j], a);
    hp[kg][j] = a;
    __syncthreads();
    if (kg == 0) {
      float acc = hp[0][j] + hp[1][j] + hp[2][j] + hp[3][j] + b1[j0 + j];
      float x3 = acc * acc * acc;
      float hj = 0.5f * acc * (1.0f + tanhf(0.7978845608028654f * (acc + 0.044715f * x3)));
      hgel[b * HC + j0 + j] = hj;
    }
  } else if (bx < 480) {
    int pb = bx - 96;
    int tile = pb % 96, ks = pb / 96;
    gemm_tn_part(U0, LcatF, Ppart + (size_t)ks * 98304, (tile & 15) * 32, (tile >> 4) * 32,
                 ks * 512, 512, DIN, P1, P1, As, Bs, t);
  } else {
    int gb = bx - 480;
    int tile = gb % 36, ks = gb / 36;
    gemm_tn_part(LcatF, LcatF, GLLpart + (size_t)ks * 36864, (tile % 6) * 32, (tile / 6) * 32,
                 ks * 512, 512, P1, P1, P1, As, Bs, t);
  }
}

// ---------------- pre2b: reduce split-K partials into E[:,192:] and GLL ----------------
__global__ __launch_bounds__(256) void k_pre2b(const float* __restrict__ Ppart,
                                               const float* __restrict__ GLLpart,
                                               float* __restrict__ E, float* __restrict__ GLL) {
  int idx = blockIdx.x * 256 + threadIdx.x;
  if (idx < 98304) {
    float s = Ppart[idx] + Ppart[98304 + idx] + Ppart[2 * 98304 + idx] + Ppart[3 * 98304 + idx];
    int d = idx / P1, j = idx - d * P1;
    E[(size_t)d * P2 + P1 + j] = s;
  } else if (idx < 98304 + 36864) {
    int i2 = idx - 98304;
    GLL[i2] = GLLpart[i2] + GLLpart[36864 + i2] + GLLpart[2 * 36864 + i2] + GLLpart[3 * 36864 + i2];
  }
}

// ---------------- pre3: GE gemm (0..143) || pack_B (144..1359) || packE (1360..2127) ----------
__global__ __launch_bounds__(256) void k_pre3(const float* __restrict__ E,
                                              const float* __restrict__ Wsh, const float* __restrict__ U0,
                                              const float* __restrict__ LcatF,
                                              float* __restrict__ GE, short* __restrict__ Bcat,
                                              short* __restrict__ Eb16, short* __restrict__ Etb16) {
  int bx = blockIdx.x, t = threadIdx.x;
  __shared__ float As[32][33], Bs[32][33];
  if (bx < 144) {
    gemm_tn_part(E, E, GE, (bx % 12) * 32, (bx / 12) * 32, 0, DIN, P2, P2, P2, As, Bs, t);
  } else if (bx < 1360) {
    int idx = (bx - 144) * 256 + t;
    int row = idx / 152, g = idx - row * 152;
    const float* src;
    if (g < 64)       src = Wsh + (size_t)row * DIN + g * 8;
    else if (g < 128) src = U0 + (size_t)row * DIN + (g - 64) * 8;
    else              src = LcatF + (size_t)row * P1 + (g - 128) * 8;
    short8 o;
#pragma unroll
    for (int e = 0; e < 8; ++e) o[e] = bf16r(src[e]);
    *(short8*)(Bcat + (size_t)row * 1216 + g * 8) = o;
  } else {
    int idx = (bx - 1360) * 256 + t;
    int d = idx / P2, q = idx - d * P2;
    short v = bf16r(E[idx]);
    Eb16[idx] = v;
    Etb16[(size_t)q * DIN + d] = v;
  }
}

// ---------------- pre4: norms + coeff + gate + cp, single block 512 threads ----------------
__global__ __launch_bounds__(512) void k_pre4(const float* __restrict__ GLL, const float* __restrict__ GE,
                                              const float* __restrict__ hgel,
                                              const float* __restrict__ Wc, const float* __restrict__ bc,
                                              const float* __restrict__ Wg, const float* __restrict__ bg,
                                              float* __restrict__ gate, float* __restrict__ cp) {
  __shared__ float nrm[16];
  int t = threadIdx.x;
  int k = t >> 5, lane = t & 31;
  float s1 = 0.f, s2 = 0.f, s3 = 0.f;
  for (int idx = lane; idx < RANK_ * RANK_; idx += 32) {
    int r = idx / RANK_, s = idx - r * RANK_;
    int p = k * RANK_ + r, q = k * RANK_ + s;
    float gll = GLL[p * P1 + q];
    float grr = GE[p * P2 + q];
    float gpp = GE[(P1 + p) * P2 + (P1 + q)];
    float gpr = GE[(P1 + p) * P2 + q];
    float gprt = GE[(P1 + q) * P2 + p];
    s1 += gll * grr;
    s2 += gpp * grr;
    s3 += gpr * gprt;
  }
#pragma unroll
  for (int off = 16; off > 0; off >>= 1) {
    s1 += __shfl_down(s1, off, 32);
    s2 += __shfl_down(s2, off, 32);
    s3 += __shfl_down(s3, off, 32);
  }
  if (lane == 0) nrm[k] = sqrtf(fmaxf(s1 - 0.5f * (s2 + s3), 0.0f));
  int bb = t >> 4, kk = t & 15;
  float c = bc[kk];
  const float* hb = hgel + bb * HC;
  for (int q = 0; q < HC; ++q) c = fmaf(hb[q], Wc[q * K_ + kk], c);
  if (t < B_) {
    float g = bg[0];
    const float* hb2 = hgel + t * HC;
    for (int q = 0; q < HC; ++q) g = fmaf(hb2[q], Wg[q], g);
    gate[t] = 1.0f / (1.0f + expf(-g));
  }
  __syncthreads();
  cp[t] = c / fmaxf(nrm[kk], 1e-6f);
}

// ---------------- pre5: m0b (0..575) || packEc (576..3647) ----------------
__global__ __launch_bounds__(256) void k_pre5(const float* __restrict__ GLL, const float* __restrict__ GE,
                                              const float* __restrict__ E, const float* __restrict__ cp,
                                              short* __restrict__ M0b, short* __restrict__ Ecb) {
  int bx = blockIdx.x, t = threadIdx.x;
  if (bx < 576) {
    int idx = bx * 256 + t;
    if (idx >= P2 * P2) return;
    int p = idx / P2, q = idx - p * P2;
    float v;
    if (p < P1) {
      if (q < P1) v = GLL[p * P1 + q] - 0.75f * GE[(P1 + p) * P2 + (P1 + q)];
      else        v = -0.25f * GE[(P1 + p) * P2 + (q - P1)];
    } else {
      if (q < P1) v = -0.25f * GE[(P1 + q) * P2 + (p - P1)];
      else        v = 0.25f * GE[(p - P1) * P2 + (q - P1)];
    }
    M0b[idx] = bf16r(v);
  } else {
    int idx = (bx - 576) * 256 + t;
    int b = idx / (DIN * 48);
    int rem = idx - b * DIN * 48;
    int d = rem / 48, g = rem - d * 48;
    int q0 = g * 8;
    const float* src = E + (size_t)d * P2 + q0;
    const float* cpb = cp + b * K_;
    short8 o;
#pragma unroll
    for (int e = 0; e < 8; ++e) {
      int q = q0 + e;
      int kidx = (q % P1) / RANK_;
      o[e] = bf16r(src[e] * cpb[kidx]);
    }
    *(short8*)(Ecb + ((size_t)b * DIN + d) * P2 + q0) = o;
  }
}

// ---------------- generic batched bf16 MFMA NT kernel: C = A @ B^T (bf16 out) ----------------
template<int MSZ, int NSZ, int KD>
__global__ __launch_bounds__(256) void k_mf_nt16(const short* __restrict__ A,
                                                 const short* __restrict__ B,
                                                 short* __restrict__ C) {
  int b = blockIdx.z;
  const short* Ab = A + (size_t)b * MSZ * KD;
  short* Cb = C + (size_t)b * MSZ * NSZ;
  int c0 = blockIdx.x * 64, r0 = blockIdx.y * 64;
  __shared__ short As[64][40], Bs[64][40];
  int t = threadIdx.x;
  int l = t & 63, wid = t >> 6;
  int wr = wid >> 1, wc = wid & 1;
  int fr = l & 15, fq = l >> 4;
  int row = t >> 2, cg = t & 3;
  f32x4 acc[2][2] = {};
  for (int kt = 0; kt < KD / 32; ++kt) {
    *(short8*)&As[row][cg * 8] = *(const short8*)(Ab + (size_t)(r0 + row) * KD + kt * 32 + cg * 8);
    *(short8*)&Bs[row][cg * 8] = *(const short8*)(B + (size_t)(c0 + row) * KD + kt * 32 + cg * 8);
    __syncthreads();
    short8 af[2], bf[2];
#pragma unroll
    for (int m = 0; m < 2; ++m) af[m] = *(const short8*)&As[wr * 32 + m * 16 + fr][fq * 8];
#pragma unroll
    for (int n = 0; n < 2; ++n) bf[n] = *(const short8*)&Bs[wc * 32 + n * 16 + fr][fq * 8];
#pragma unroll
    for (int m = 0; m < 2; ++m)
#pragma unroll
      for (int n = 0; n < 2; ++n)
        acc[m][n] = __builtin_amdgcn_mfma_f32_16x16x32_bf16(af[m], bf[n], acc[m][n], 0, 0, 0);
    __syncthreads();
  }
#pragma unroll
  for (int m = 0; m < 2; ++m)
#pragma unroll
    for (int n = 0; n < 2; ++n)
#pragma unroll
      for (int j = 0; j < 4; ++j)
        Cb[(size_t)(r0 + wr * 32 + m * 16 + fq * 4 + j) * NSZ + c0 + wc * 32 + n * 16 + fr] =
            bf16r(acc[m][n][j]);
}

// ---------------- k_mf_G: G = I + Hb @ Ecb^T (f32 out, both batched) ----------------
__global__ __launch_bounds__(256) void k_mf_G(const short* __restrict__ H,
                                              const short* __restrict__ Ec,
                                              float* __restrict__ G) {
  int b = blockIdx.z;
  const short* Ab = H + (size_t)b * DIN * P2;
  const short* Bb = Ec + (size_t)b * DIN * P2;
  float* Gb = G + (size_t)b * DIN * DIN;
  int c0 = blockIdx.x * 64, r0 = blockIdx.y * 64;
  __shared__ short As[64][40], Bs[64][40];
  int t = threadIdx.x;
  int l = t & 63, wid = t >> 6;
  int wr = wid >> 1, wc = wid & 1;
  int fr = l & 15, fq = l >> 4;
  int row = t >> 2, cg = t & 3;
  f32x4 acc[2][2] = {};
  for (int kt = 0; kt < P2 / 32; ++kt) {
    *(short8*)&As[row][cg * 8] = *(const short8*)(Ab + (size_t)(r0 + row) * P2 + kt * 32 + cg * 8);
    *(short8*)&Bs[row][cg * 8] = *(const short8*)(Bb + (size_t)(c0 + row) * P2 + kt * 32 + cg * 8);
    __syncthreads();
    short8 af[2], bf[2];
#pragma unroll
    for (int m = 0; m < 2; ++m) af[m] = *(const short8*)&As[wr * 32 + m * 16 + fr][fq * 8];
#pragma unroll
    for (int n = 0; n < 2; ++n) bf[n] = *(const short8*)&Bs[wc * 32 + n * 16 + fr][fq * 8];
#pragma unroll
    for (int m = 0; m < 2; ++m)
#pragma unroll
      for (int n = 0; n < 2; ++n)
        acc[m][n] = __builtin_amdgcn_mfma_f32_16x16x32_bf16(af[m], bf[n], acc[m][n], 0, 0, 0);
    __syncthreads();
  }
#pragma unroll
  for (int m = 0; m < 2; ++m)
#pragma unroll
    for (int n = 0; n < 2; ++n)
#pragma unroll
      for (int j = 0; j < 4; ++j) {
        int gr = r0 + wr * 32 + m * 16 + fq * 4 + j;
        int gc = c0 + wc * 32 + n * 16 + fr;
        Gb[(size_t)gr * DIN + gc] = acc[m][n][j] + (gr == gc ? 1.0f : 0.0f);
      }
}

// ---------------- k_chol_dp2: panel step + bf16 side-channel for trif ----------------
// role 0 inverse now in rank-1 back-substitution form (short critical path).
__global__ __launch_bounds__(64) void k_chol_dp2(float* __restrict__ G, short* __restrict__ Rb,
                                                 short* __restrict__ Wdb, int j0) {
  int b = blockIdx.y;
  int role = blockIdx.x;
  float* Gb = G + (size_t)b * DIN * DIN;
  short* Rbb = Rb + (size_t)b * DIN * DIN;
  __shared__ float D[64][65];
  __shared__ float dinvs[64];
  int t = threadIdx.x;
#pragma unroll 8
  for (int i = 0; i < 64; ++i) D[i][t] = Gb[(size_t)(j0 + i) * DIN + j0 + t];
  __syncthreads();
  {
    float col[64];
#pragma unroll
    for (int i = 0; i < 64; ++i) col[i] = D[i][t];
#pragma unroll
    for (int j = 0; j < 64; ++j) {
      float djj = __shfl(col[j], j);
      float rjj = sqrtf(fmaxf(djj, 1e-30f));
      float rinv = 1.0f / rjj;
      if (t == j) col[j] = rjj;
      else if (t > j) col[j] *= rinv;
      float djt = col[j];
#pragma unroll
      for (int i = j + 1; i < 64; ++i) {
        float rji = __shfl(col[j], i);
        if (i <= t) col[i] = fmaf(-rji, djt, col[i]);
      }
    }
#pragma unroll
    for (int i = 0; i < 64; ++i) D[i][t] = (i <= t) ? col[i] : 0.0f;
    dinvs[t] = 1.0f / col[t];
  }
  __syncthreads();
  if (role == 0) {
    // rank-1 back-substitution: solve D * w = e_t (lane t owns column t of W = D^-1)
    float w[64];
#pragma unroll
    for (int i = 0; i < 64; ++i) w[i] = (i == t) ? 1.0f : 0.0f;
#pragma unroll
    for (int jj = 63; jj >= 0; --jj) {
      float wj = w[jj] * dinvs[jj];
      w[jj] = wj;
#pragma unroll
      for (int i = 0; i < 64; ++i)
        if (i < jj) w[i] = fmaf(-D[i][jj], wj, w[i]);
    }
    short* Wp = Wdb + ((size_t)b * 8 + (j0 >> 6)) * 4096;
#pragma unroll 4
    for (int i = 0; i < 64; ++i) Wp[i * 64 + t] = bf16r(w[i]);
  } else {
    int c = j0 + 64 + (role - 1) * 64 + t;
    float a[64];
#pragma unroll
    for (int i = 0; i < 64; ++i) a[i] = Gb[(size_t)(j0 + i) * DIN + c];
#pragma unroll
    for (int j = 0; j < 64; ++j) {
      float aj = a[j] * dinvs[j];
      a[j] = aj;
#pragma unroll
      for (int i = j + 1; i < 64; ++i) a[i] = fmaf(-D[j][i], aj, a[i]);
    }
#pragma unroll
    for (int i = 0; i < 64; ++i) {
      Gb[(size_t)(j0 + i) * DIN + c] = a[i];
      Rbb[(size_t)(j0 + i) * DIN + c] = bf16r(a[i]);
    }
  }
}

// ---------------- k_chol_tr: trailing update C -= P^T P over 64x64 tile pairs ----------------
__global__ __launch_bounds__(256) void k_chol_tr(float* __restrict__ G, int j0, int nt) {
  int b = blockIdx.y;
  int pi = blockIdx.x;
  int ti = 0, accum = 0;
  while (pi >= accum + (nt - ti)) { accum += nt - ti; ++ti; }
  int tc = ti + (pi - accum);
  float* Gb = G + (size_t)b * DIN * DIN;
  __shared__ float As[64][65], Bs[64][65];
  int t = threadIdx.x;
  int ibase = j0 + 64 + ti * 64, cbase = j0 + 64 + tc * 64;
  for (int idx = t; idx < 4096; idx += 256) {
    int j = idx >> 6, c = idx & 63;
    As[j][c] = Gb[(size_t)(j0 + j) * DIN + ibase + c];
    Bs[j][c] = Gb[(size_t)(j0 + j) * DIN + cbase + c];
  }
  __syncthreads();
  int tx = t & 15, ty = t >> 4;
  float acc[4][4] = {};
#pragma unroll 8
  for (int k = 0; k < 64; ++k) {
    float a[4], bv[4];
#pragma unroll
    for (int u = 0; u < 4; ++u) a[u] = As[k][ty * 4 + u];
#pragma unroll
    for (int v = 0; v < 4; ++v) bv[v] = Bs[k][tx * 4 + v];
#pragma unroll
    for (int u = 0; u < 4; ++u)
#pragma unroll
      for (int v = 0; v < 4; ++v) acc[u][v] = fmaf(a[u], bv[v], acc[u][v]);
  }
#pragma unroll
  for (int u = 0; u < 4; ++u) {
    size_t ro = (size_t)(ibase + ty * 4 + u) * DIN + cbase + tx * 4;
#pragma unroll
    for (int v = 0; v < 4; ++v) Gb[ro + v] -= acc[u][v];
  }
}

// ---------------- k_trif: fused trisolve (bf16 R/Wd operands, XCD-chunked blocks) ----------------
__global__ __launch_bounds__(256) void k_trif(const float* __restrict__ x, const short* __restrict__ Rb,
                                              const short* __restrict__ Wdb, short* __restrict__ ybf,
                                              short* __restrict__ ycb) {
  int wg = blockIdx.x;
  int swz = (wg & 7) * 64 + (wg >> 3);  // XCD-chunked bijective (512 % 8 == 0)
  int b = swz >> 4;
  int n0 = (swz & 15) * 16;
  const short* Rbb = Rb + (size_t)b * DIN * DIN;
  const float* xb = x + ((size_t)b * N_ + n0) * DIN;
  __shared__ float Yl[16][517];
  __shared__ float Rs[64][65];
  __shared__ float Wds[64][65];
  __shared__ float Ytmp[16][69];
  int t = threadIdx.x;
  for (int idx = t; idx < 16 * DIN; idx += 256)
    Yl[idx >> 9][idx & 511] = xb[(size_t)(idx >> 9) * DIN + (idx & 511)];
  __syncthreads();
  int r = t & 15, cg = t >> 4;
  for (int p = 7; p >= 0; --p) {
    int j0 = p * 64;
    int kN = DIN - j0 - 64;
    float acc[4] = {0.f, 0.f, 0.f, 0.f};
    for (int kb = 0; kb < kN; kb += 64) {
      for (int idx = t; idx < 4096; idx += 256) {
        int kk = idx & 63, c = idx >> 6;
        Rs[kk][c] = b16f(Rbb[(size_t)(j0 + c) * DIN + j0 + 64 + kb + kk]);
      }
      __syncthreads();
#pragma unroll 8
      for (int kk = 0; kk < 64; ++kk) {
        float a = Yl[r][j0 + 64 + kb + kk];
#pragma unroll
        for (int v = 0; v < 4; ++v) acc[v] = fmaf(a, Rs[kk][cg * 4 + v], acc[v]);
      }
      __syncthreads();
    }
#pragma unroll
    for (int v = 0; v < 4; ++v) Ytmp[r][cg * 4 + v] = Yl[r][j0 + cg * 4 + v] - acc[v];
    const short* Wp = Wdb + ((size_t)b * 8 + p) * 4096;
    for (int idx = t; idx < 4096; idx += 256) Wds[idx >> 6][idx & 63] = b16f(Wp[idx]);
    __syncthreads();
    float o[4] = {0.f, 0.f, 0.f, 0.f};
#pragma unroll 8
    for (int jj = 0; jj < 64; ++jj) {
      float a = Ytmp[r][jj];
#pragma unroll
      for (int v = 0; v < 4; ++v) o[v] = fmaf(a, Wds[cg * 4 + v][jj], o[v]);
    }
    __syncthreads();
#pragma unroll
    for (int v = 0; v < 4; ++v) Yl[r][j0 + cg * 4 + v] = o[v];
    __syncthreads();
  }
  for (int idx = t; idx < 16 * DIN; idx += 256) {
    int rr = idx >> 9, c = idx & 511;
    float yv = Yl[rr][c];
    float xv = xb[(size_t)rr * DIN + c];
    size_t gi = ((size_t)b * N_ + n0 + rr) * DIN + c;
    ybf[gi] = bf16r(yv);
    ycb[gi] = bf16r(yv - xv);
  }
}

// ---------------- k_yEuv: yE = y @ E (MFMA) with fused vb epilogue ----------------
__global__ __launch_bounds__(256) void k_yEuv(const short* __restrict__ A,
                                              const short* __restrict__ B,
                                              const float* __restrict__ cp,
                                              const float* __restrict__ gate,
                                              short* __restrict__ C, short* __restrict__ vb) {
  int b = blockIdx.z;
  const short* Ab = A + (size_t)b * N_ * DIN;
  short* Cb = C + (size_t)b * N_ * P2;
  int c0 = blockIdx.x * 64, r0 = blockIdx.y * 64;
  __shared__ short As[64][40], Bs[64][40];
  __shared__ float cps[K_];
  int t = threadIdx.x;
  if (t < K_) cps[t] = cp[b * K_ + t];
  int l = t & 63, wid = t >> 6;
  int wr = wid >> 1, wc = wid & 1;
  int fr = l & 15, fq = l >> 4;
  int row = t >> 2, cg = t & 3;
  f32x4 acc[2][2] = {};
  __syncthreads();
  for (int kt = 0; kt < DIN / 32; ++kt) {
    *(short8*)&As[row][cg * 8] = *(const short8*)(Ab + (size_t)(r0 + row) * DIN + kt * 32 + cg * 8);
    *(short8*)&Bs[row][cg * 8] = *(const short8*)(B + (size_t)(c0 + row) * DIN + kt * 32 + cg * 8);
    __syncthreads();
    short8 af[2], bf[2];
#pragma unroll
    for (int m = 0; m < 2; ++m) af[m] = *(const short8*)&As[wr * 32 + m * 16 + fr][fq * 8];
#pragma unroll
    for (int n = 0; n < 2; ++n) bf[n] = *(const short8*)&Bs[wc * 32 + n * 16 + fr][fq * 8];
#pragma unroll
    for (int m = 0; m < 2; ++m)
#pragma unroll
      for (int n = 0; n < 2; ++n)
        acc[m][n] = __builtin_amdgcn_mfma_f32_16x16x32_bf16(af[m], bf[n], acc[m][n], 0, 0, 0);
    __syncthreads();
  }
  float gt = gate[b];
#pragma unroll
  for (int m = 0; m < 2; ++m)
#pragma unroll
    for (int n = 0; n < 2; ++n)
#pragma unroll
      for (int j = 0; j < 4; ++j) {
        int gr = r0 + wr * 32 + m * 16 + fq * 4 + j;
        int gc = c0 + wc * 32 + n * 16 + fr;
        float v = acc[m][n][j];
        Cb[(size_t)gr * P2 + gc] = bf16r(v);
        if (gc < P1)
          vb[((size_t)b * N_ + gr) * P1 + gc] = bf16r(gt * cps[gc / RANK_] * v);
      }
}

// ---------------- k_mf_w: wb = bf16(gate*(yc - u @ E^T)) ----------------
__global__ __launch_bounds__(256) void k_mf_w(const short* __restrict__ yE16,
                                              const short* __restrict__ Eb,
                                              const short* __restrict__ ycb,
                                              const float* __restrict__ cp,
                                              const float* __restrict__ gate,
                                              short* __restrict__ wb) {
  int b = blockIdx.z;
  const short* yEb = yE16 + (size_t)b * N_ * P2;
  int c0 = blockIdx.x * 64, r0 = blockIdx.y * 64;
  __shared__ short As[64][40], Bs[64][40];
  __shared__ float cps[K_];
  int t = threadIdx.x;
  if (t < K_) cps[t] = 0.5f * cp[b * K_ + t];
  int l = t & 63, wid = t >> 6;
  int wr = wid >> 1, wc = wid & 1;
  int fr = l & 15, fq = l >> 4;
  int row = t >> 2, cg = t & 3;
  f32x4 acc[2][2] = {};
  __syncthreads();
  for (int kt = 0; kt < P2 / 32; ++kt) {
    int ksrc0 = (kt * 32 + P1) % P2;
    short8 raw = *(const short8*)(yEb + (size_t)(r0 + row) * P2 + ksrc0 + cg * 8);
    short8 oa;
#pragma unroll
    for (int e = 0; e < 8; ++e) {
      int q = kt * 32 + cg * 8 + e;
      int kidx = (q % P1) / RANK_;
      oa[e] = bf16r(b16f(raw[e]) * cps[kidx]);
    }
    *(short8*)&As[row][cg * 8] = oa;
    *(short8*)&Bs[row][cg * 8] = *(const short8*)(Eb + (size_t)(c0 + row) * P2 + kt * 32 + cg * 8);
    __syncthreads();
    short8 af[2], bf[2];
#pragma unroll
    for (int m = 0; m < 2; ++m) af[m] = *(const short8*)&As[wr * 32 + m * 16 + fr][fq * 8];
#pragma unroll
    for (int n = 0; n < 2; ++n) bf[n] = *(const short8*)&Bs[wc * 32 + n * 16 + fr][fq * 8];
#pragma unroll
    for (int m = 0; m < 2; ++m)
#pragma unroll
      for (int n = 0; n < 2; ++n)
        acc[m][n] = __builtin_amdgcn_mfma_f32_16x16x32_bf16(af[m], bf[n], acc[m][n], 0, 0, 0);
    __syncthreads();
  }
  float gt = gate[b];
#pragma unroll
  for (int m = 0; m < 2; ++m)
#pragma unroll
    for (int n = 0; n < 2; ++n)
#pragma unroll
      for (int j = 0; j < 4; ++j) {
        int gr = r0 + wr * 32 + m * 16 + fq * 4 + j;
        int gc = c0 + wc * 32 + n * 16 + fr;
        size_t gi = ((size_t)b * N_ + gr) * DIN + gc;
        wb[gi] = bf16r(gt * (b16f(ycb[gi]) - acc[m][n][j]));
      }
}

// ---------------- K13: MFMA fused output GEMM: out = [x|w|v] @ Bcat^T + bias ----------------
__device__ inline short8 loadA8(const float* __restrict__ x, const short* __restrict__ wb,
                                const short* __restrict__ vb, int grow, int k0) {
  if (k0 < 512) {
    const float* p = x + (size_t)grow * 512 + k0;
    float4 f0 = *(const float4*)p;
    float4 f1 = *(const float4*)(p + 4);
    short8 o;
    o[0] = bf16r(f0.x); o[1] = bf16r(f0.y); o[2] = bf16r(f0.z); o[3] = bf16r(f0.w);
    o[4] = bf16r(f1.x); o[5] = bf16r(f1.y); o[6] = bf16r(f1.z); o[7] = bf16r(f1.w);
    return o;
  } else if (k0 < 1024) {
    return *(const short8*)(wb + (size_t)grow * 512 + k0 - 512);
  } else {
    return *(const short8*)(vb + (size_t)grow * 192 + k0 - 1024);
  }
}

__global__ __launch_bounds__(256) void k_final(
    const float* __restrict__ x, const short* __restrict__ wb, const short* __restrict__ vb,
    const short* __restrict__ Bcat, const float* __restrict__ bias, float* __restrict__ out) {
  __shared__ short As[2][4096];
  __shared__ short Bs[2][4096];
  int t = threadIdx.x;
  int c0 = blockIdx.x * 128;
  int r0 = blockIdx.y * 128;
  int l = t & 63, wid = t >> 6;
  int wr = wid >> 1, wc = wid & 1;
  int fr = l & 15, fq = l >> 4;
  f32x4 acc[4][4] = {};
  short8 ra0, ra1, rb0, rb1;
  const int row0 = t >> 2, c8 = t & 3;
  const int row1 = row0 + 64;
  ra0 = loadA8(x, wb, vb, r0 + row0, c8 * 8);
  ra1 = loadA8(x, wb, vb, r0 + row1, c8 * 8);
  rb0 = *(const short8*)(Bcat + (size_t)(c0 + row0) * 1216 + c8 * 8);
  rb1 = *(const short8*)(Bcat + (size_t)(c0 + row1) * 1216 + c8 * 8);
  *(short8*)&As[0][row0 * 32 + c8 * 8] = ra0;
  *(short8*)&As[0][row1 * 32 + c8 * 8] = ra1;
  *(short8*)&Bs[0][row0 * 32 + c8 * 8] = rb0;
  *(short8*)&Bs[0][row1 * 32 + c8 * 8] = rb1;
  __syncthreads();
  for (int kt = 0; kt < 38; ++kt) {
    int cur = kt & 1;
    if (kt + 1 < 38) {
      int k0 = (kt + 1) * 32;
      ra0 = loadA8(x, wb, vb, r0 + row0, k0 + c8 * 8);
      ra1 = loadA8(x, wb, vb, r0 + row1, k0 + c8 * 8);
      rb0 = *(const short8*)(Bcat + (size_t)(c0 + row0) * 1216 + k0 + c8 * 8);
      rb1 = *(const short8*)(Bcat + (size_t)(c0 + row1) * 1216 + k0 + c8 * 8);
    }
    short8 af[4], bf[4];
#pragma unroll
    for (int m = 0; m < 4; ++m)
      af[m] = *(const short8*)&As[cur][(wr * 64 + m * 16 + fr) * 32 + fq * 8];
#pragma unroll
    for (int n = 0; n < 4; ++n)
      bf[n] = *(const short8*)&Bs[cur][(wc * 64 + n * 16 + fr) * 32 + fq * 8];
#pragma unroll
    for (int m = 0; m < 4; ++m)
#pragma unroll
      for (int n = 0; n < 4; ++n)
        acc[m][n] = __builtin_amdgcn_mfma_f32_16x16x32_bf16(af[m], bf[n], acc[m][n], 0, 0, 0);
    __syncthreads();
    if (kt + 1 < 38) {
      int nxt = cur ^ 1;
      *(short8*)&As[nxt][row0 * 32 + c8 * 8] = ra0;
      *(short8*)&As[nxt][row1 * 32 + c8 * 8] = ra1;
      *(short8*)&Bs[nxt][row0 * 32 + c8 * 8] = rb0;
      *(short8*)&Bs[nxt][row1 * 32 + c8 * 8] = rb1;
    }
    __syncthreads();
  }
#pragma unroll
  for (int n = 0; n < 4; ++n) {
    int col = c0 + wc * 64 + n * 16 + fr;
    float bv = bias[col];
#pragma unroll
    for (int m = 0; m < 4; ++m) {
      int rbase = r0 + wr * 64 + m * 16 + fq * 4;
#pragma unroll
      for (int j = 0; j < 4; ++j)
        out[(size_t)(rbase + j) * DOUT + col] = acc[m][n][j] + bv;
    }
  }
}

extern "C" void kernel_launch(void* const* d_in, const int* in_sizes, int n_in,
                              void* d_out, int out_size, void* d_ws, size_t ws_size,
                              hipStream_t stream) {
  (void)in_sizes; (void)n_in; (void)out_size; (void)ws_size;
  const float* x     = (const float*)d_in[0];
  const float* Wsh   = (const float*)d_in[1];
  const float* bias  = (const float*)d_in[2];
  const float* U0    = (const float*)d_in[3];
  const float* leftb = (const float*)d_in[4];
  const float* rightb= (const float*)d_in[5];
  const float* W1    = (const float*)d_in[6];
  const float* b1    = (const float*)d_in[7];
  const float* Wc    = (const float*)d_in[8];
  const float* bc    = (const float*)d_in[9];
  const float* Wg    = (const float*)d_in[10];
  const float* bg    = (const float*)d_in[11];
  float* out = (float*)d_out;

  float* wsf = (float*)d_ws;
  float* hgel  = wsf + 0;
  float* gate  = wsf + 49664;
  float* cp    = wsf + 49792;
  float* LcatF = wsf + 50304;
  float* E     = wsf + 443520;
  float* GLL   = wsf + 640128;
  float* GE    = wsf + 676992;
  short* M0b16 = (short*)(wsf + 824448);
  short* Eb16  = (short*)(wsf + 898176);
  short* Etb16 = (short*)(wsf + 996480);
  short* wb    = (short*)(wsf + 1094784);
  short* Ecb   = (short*)(wsf + 3191936);
  short* ybf   = (short*)(wsf + 3191936);
  short* vb    = (short*)(wsf + 5289088);
  short* Hb16  = (short*)(wsf + 6337664);
  short* ycb   = (short*)(wsf + 6337664);
  short* Bcat  = (short*)(wsf + 9483392);
  float* sp      = wsf + 10728576;
  float* s2p     = wsf + 10859648;
  float* Ppart   = wsf + 10990720;
  float* GLLpart = wsf + 11383936;
  // d_out layout (floats): G [0,8388608) | Rb16 [8388608,12582912) | yE16 [12582912,14155776)
  //                        | Wdb16 [14155776,14680064) — all dead before k_final overwrites
  float* G = out;
  short* Rb16 = (short*)(out + 8388608);
  short* yE16 = (short*)(out + 12582912);
  short* Wdb16 = (short*)(out + 14155776);

  k_pre1<<<256 + 1920, 256, 0, stream>>>(x, leftb, rightb, sp, s2p, LcatF, E);
  k_pre2<<<624, 256, 0, stream>>>(x, sp, s2p, W1, b1, U0, LcatF, hgel, Ppart, GLLpart);
  k_pre2b<<<528, 256, 0, stream>>>(Ppart, GLLpart, E, GLL);
  k_pre3<<<2128, 256, 0, stream>>>(E, Wsh, U0, LcatF, GE, Bcat, Eb16, Etb16);
  k_pre4<<<1, 512, 0, stream>>>(GLL, GE, hgel, Wc, bc, Wg, bg, gate, cp);
  k_pre5<<<3648, 256, 0, stream>>>(GLL, GE, E, cp, M0b16, Ecb);
  k_mf_nt16<DIN, P2, P2><<<dim3(P2 / 64, DIN / 64, B_), 256, 0, stream>>>(Ecb, M0b16, Hb16);
  k_mf_G<<<dim3(DIN / 64, DIN / 64, B_), 256, 0, stream>>>(Hb16, Ecb, G);
  // right-looking blocked Cholesky: 8 dp + 7 tr launches
  for (int p = 0; p < 8; ++p) {
    int j0 = p * 64;
    int nt = 7 - p;
    k_chol_dp2<<<dim3(nt + 1, B_), 64, 0, stream>>>(G, Rb16, Wdb16, j0);
    if (nt > 0)
      k_chol_tr<<<dim3(nt * (nt + 1) / 2, B_), 256, 0, stream>>>(G, j0, nt);
  }
  k_trif<<<512, 256, 0, stream>>>(x, Rb16, Wdb16, ybf, ycb);
  k_yEuv<<<dim3(P2 / 64, N_ / 64, B_), 256, 0, stream>>>(ybf, Etb16, cp, gate, yE16, vb);
  k_mf_w<<<dim3(DIN / 64, N_ / 64, B_), 256, 0, stream>>>(yE16, Eb16, ycb, cp, gate, wb);
  k_final<<<dim3(DOUT / 128, (B_ * N_) / 128), 256, 0, stream>>>(x, wb, vb, Bcat, bias, out);
}

// Round 16
// 1454.800 us; speedup vs baseline: 1.9430x; 1.9430x over previous
//
#include <hip/hip_runtime.h>
#include <math.h>

#define B_    32
#define N_    256
#define DIN   512
#define DOUT  2048
#define RANK_ 12
#define K_    16
#define HC    192
#define CD    1536
#define P1    192
#define P2    384

typedef short short8 __attribute__((ext_vector_type(8)));
typedef float f32x4 __attribute__((ext_vector_type(4)));

__device__ inline short bf16r(float f) {
  unsigned u = __float_as_uint(f);
  unsigned r = (u + 0x7FFFu + ((u >> 16) & 1u)) >> 16;
  return (short)r;
}
__device__ inline float b16f(short s) {
  unsigned u = ((unsigned)(unsigned short)s) << 16;
  return __uint_as_float(u);
}

// ---------------- pre1: stats partials (0..255) || copy_bases (256..2175) ----------------
__global__ __launch_bounds__(256) void k_pre1(const float* __restrict__ x,
                                              const float* __restrict__ leftb,
                                              const float* __restrict__ rightb,
                                              float* __restrict__ sp, float* __restrict__ s2p,
                                              float* __restrict__ Lcat, float* __restrict__ E) {
  int bx = blockIdx.x, t = threadIdx.x;
  if (bx < 256) {
    int b = bx >> 3, c = bx & 7;
    const float* xb = x + (size_t)b * N_ * DIN;
#pragma unroll
    for (int h2 = 0; h2 < 2; ++h2) {
      int d = t + h2 * 256;
      float s = 0.f, s2 = 0.f;
      for (int n = c * 32; n < c * 32 + 32; ++n) {
        float v = xb[(size_t)n * DIN + d];
        s += v; s2 += v * v;
      }
      sp[(size_t)(b * 8 + c) * DIN + d] = s;
      s2p[(size_t)(b * 8 + c) * DIN + d] = s2;
    }
  } else {
    int idx = (bx - 256) * 256 + t;
    const int totL = DOUT * P1;
    const int totR = DIN * P1;
    if (idx < totL) {
      int m = idx / P1, j = idx - m * P1;
      int k = j / RANK_, r = j - k * RANK_;
      Lcat[idx] = leftb[((size_t)k * DOUT + m) * RANK_ + r];
    } else if (idx < totL + totR) {
      int i2 = idx - totL;
      int d = i2 / P1, j = i2 - d * P1;
      int k = j / RANK_, r = j - k * RANK_;
      E[(size_t)d * P2 + j] = rightb[((size_t)k * DIN + d) * RANK_ + r];
    }
  }
}

// ---------------- shared TN GEMM body with K-range ----------------
__device__ inline void gemm_tn_part(const float* __restrict__ A, const float* __restrict__ B,
                                    float* __restrict__ C, int i0, int j0, int kb0, int klen,
                                    int lda, int ldb, int ldc,
                                    float (*As)[33], float (*Bs)[33], int t) {
  int ii = t & 31, j4 = (t >> 5) * 4;
  float acc[4] = {0.f, 0.f, 0.f, 0.f};
  for (int kb = kb0; kb < kb0 + klen; kb += 32) {
    for (int idx = t; idx < 1024; idx += 256) {
      int kk = idx >> 5, c = idx & 31;
      As[kk][c] = A[(size_t)(kb + kk) * lda + i0 + c];
      Bs[kk][c] = B[(size_t)(kb + kk) * ldb + j0 + c];
    }
    __syncthreads();
#pragma unroll 8
    for (int kk = 0; kk < 32; ++kk) {
      float a = As[kk][ii];
#pragma unroll
      for (int q = 0; q < 4; ++q) acc[q] = fmaf(a, Bs[kk][j4 + q], acc[q]);
    }
    __syncthreads();
  }
#pragma unroll
  for (int q = 0; q < 4; ++q) C[(size_t)(i0 + ii) * ldc + j0 + j4 + q] = acc[q];
}

// ---------------- pre2: h-GEMM (0..95) || Pcat splitK (96..479) || GLL splitK (480..623) ----
__global__ __launch_bounds__(256) void k_pre2(const float* __restrict__ x,
                                              const float* __restrict__ sp, const float* __restrict__ s2p,
                                              const float* __restrict__ W1, const float* __restrict__ b1,
                                              const float* __restrict__ U0, const float* __restrict__ LcatF,
                                              float* __restrict__ hgel,
                                              float* __restrict__ Ppart, float* __restrict__ GLLpart) {
  int bx = blockIdx.x, t = threadIdx.x;
  __shared__ float As[32][33], Bs[32][33];
  __shared__ float zsh[CD];
  __shared__ float hp[4][64];
  if (bx < 96) {
    int b = bx / 3, jt = bx % 3;
    int j0 = jt * 64;
    for (int d = t; d < CD; d += 256) {
      float v;
      if (d < DIN) {
        v = x[(size_t)b * N_ * DIN + d];
      } else {
        int dd = d & 511;
        float s = 0.f;
#pragma unroll
        for (int c2 = 0; c2 < 8; ++c2) s += sp[(size_t)(b * 8 + c2) * DIN + dd];
        float mean = s * (1.0f / N_);
        if (d < 2 * DIN) v = mean;
        else {
          float s2 = 0.f;
#pragma unroll
          for (int c2 = 0; c2 < 8; ++c2) s2 += s2p[(size_t)(b * 8 + c2) * DIN + dd];
          v = s2 * (1.0f / N_) - mean * mean;
        }
      }
      zsh[d] = v;
    }
    __syncthreads();
    int j = t & 63, kg = t >> 6;
    float a = 0.f;
    for (int d = kg * 384; d < kg * 384 + 384; ++d)
      a = fmaf(zsh[d], W1[(size_t)d * HC + j0 + j], a);
    hp[kg][j] = a;
    __syncthreads();
    if (kg == 0) {
      float acc = hp[0][j] + hp[1][j] + hp[2][j] + hp[3][j] + b1[j0 + j];
      float x3 = acc * acc * acc;
      float hj = 0.5f * acc * (1.0f + tanhf(0.7978845608028654f * (acc + 0.044715f * x3)));
      hgel[b * HC + j0 + j] = hj;
    }
  } else if (bx < 480) {
    int pb = bx - 96;
    int tile = pb % 96, ks = pb / 96;
    gemm_tn_part(U0, LcatF, Ppart + (size_t)ks * 98304, (tile & 15) * 32, (tile >> 4) * 32,
                 ks * 512, 512, DIN, P1, P1, As, Bs, t);
  } else {
    int gb = bx - 480;
    int tile = gb % 36, ks = gb / 36;
    gemm_tn_part(LcatF, LcatF, GLLpart + (size_t)ks * 36864, (tile % 6) * 32, (tile / 6) * 32,
                 ks * 512, 512, P1, P1, P1, As, Bs, t);
  }
}

// ---------------- pre2b: reduce split-K partials into E[:,192:] and GLL ----------------
__global__ __launch_bounds__(256) void k_pre2b(const float* __restrict__ Ppart,
                                               const float* __restrict__ GLLpart,
                                               float* __restrict__ E, float* __restrict__ GLL) {
  int idx = blockIdx.x * 256 + threadIdx.x;
  if (idx < 98304) {
    float s = Ppart[idx] + Ppart[98304 + idx] + Ppart[2 * 98304 + idx] + Ppart[3 * 98304 + idx];
    int d = idx / P1, j = idx - d * P1;
    E[(size_t)d * P2 + P1 + j] = s;
  } else if (idx < 98304 + 36864) {
    int i2 = idx - 98304;
    GLL[i2] = GLLpart[i2] + GLLpart[36864 + i2] + GLLpart[2 * 36864 + i2] + GLLpart[3 * 36864 + i2];
  }
}

// ---------------- pre3: GE gemm (0..143) || pack_B (144..1359) || packE (1360..2127) ----------
__global__ __launch_bounds__(256) void k_pre3(const float* __restrict__ E,
                                              const float* __restrict__ Wsh, const float* __restrict__ U0,
                                              const float* __restrict__ LcatF,
                                              float* __restrict__ GE, short* __restrict__ Bcat,
                                              short* __restrict__ Eb16, short* __restrict__ Etb16) {
  int bx = blockIdx.x, t = threadIdx.x;
  __shared__ float As[32][33], Bs[32][33];
  if (bx < 144) {
    gemm_tn_part(E, E, GE, (bx % 12) * 32, (bx / 12) * 32, 0, DIN, P2, P2, P2, As, Bs, t);
  } else if (bx < 1360) {
    int idx = (bx - 144) * 256 + t;
    int row = idx / 152, g = idx - row * 152;
    const float* src;
    if (g < 64)       src = Wsh + (size_t)row * DIN + g * 8;
    else if (g < 128) src = U0 + (size_t)row * DIN + (g - 64) * 8;
    else              src = LcatF + (size_t)row * P1 + (g - 128) * 8;
    short8 o;
#pragma unroll
    for (int e = 0; e < 8; ++e) o[e] = bf16r(src[e]);
    *(short8*)(Bcat + (size_t)row * 1216 + g * 8) = o;
  } else {
    int idx = (bx - 1360) * 256 + t;
    int d = idx / P2, q = idx - d * P2;
    short v = bf16r(E[idx]);
    Eb16[idx] = v;
    Etb16[(size_t)q * DIN + d] = v;
  }
}

// ---------------- pre4: norms + coeff + gate + cp, single block 512 threads ----------------
__global__ __launch_bounds__(512) void k_pre4(const float* __restrict__ GLL, const float* __restrict__ GE,
                                              const float* __restrict__ hgel,
                                              const float* __restrict__ Wc, const float* __restrict__ bc,
                                              const float* __restrict__ Wg, const float* __restrict__ bg,
                                              float* __restrict__ gate, float* __restrict__ cp) {
  __shared__ float nrm[16];
  int t = threadIdx.x;
  int k = t >> 5, lane = t & 31;
  float s1 = 0.f, s2 = 0.f, s3 = 0.f;
  for (int idx = lane; idx < RANK_ * RANK_; idx += 32) {
    int r = idx / RANK_, s = idx - r * RANK_;
    int p = k * RANK_ + r, q = k * RANK_ + s;
    float gll = GLL[p * P1 + q];
    float grr = GE[p * P2 + q];
    float gpp = GE[(P1 + p) * P2 + (P1 + q)];
    float gpr = GE[(P1 + p) * P2 + q];
    float gprt = GE[(P1 + q) * P2 + p];
    s1 += gll * grr;
    s2 += gpp * grr;
    s3 += gpr * gprt;
  }
#pragma unroll
  for (int off = 16; off > 0; off >>= 1) {
    s1 += __shfl_down(s1, off, 32);
    s2 += __shfl_down(s2, off, 32);
    s3 += __shfl_down(s3, off, 32);
  }
  if (lane == 0) nrm[k] = sqrtf(fmaxf(s1 - 0.5f * (s2 + s3), 0.0f));
  int bb = t >> 4, kk = t & 15;
  float c = bc[kk];
  const float* hb = hgel + bb * HC;
  for (int q = 0; q < HC; ++q) c = fmaf(hb[q], Wc[q * K_ + kk], c);
  if (t < B_) {
    float g = bg[0];
    const float* hb2 = hgel + t * HC;
    for (int q = 0; q < HC; ++q) g = fmaf(hb2[q], Wg[q], g);
    gate[t] = 1.0f / (1.0f + expf(-g));
  }
  __syncthreads();
  cp[t] = c / fmaxf(nrm[kk], 1e-6f);
}

// ---------------- pre5: m0b (0..575) || packEc (576..3647) ----------------
__global__ __launch_bounds__(256) void k_pre5(const float* __restrict__ GLL, const float* __restrict__ GE,
                                              const float* __restrict__ E, const float* __restrict__ cp,
                                              short* __restrict__ M0b, short* __restrict__ Ecb) {
  int bx = blockIdx.x, t = threadIdx.x;
  if (bx < 576) {
    int idx = bx * 256 + t;
    if (idx >= P2 * P2) return;
    int p = idx / P2, q = idx - p * P2;
    float v;
    if (p < P1) {
      if (q < P1) v = GLL[p * P1 + q] - 0.75f * GE[(P1 + p) * P2 + (P1 + q)];
      else        v = -0.25f * GE[(P1 + p) * P2 + (q - P1)];
    } else {
      if (q < P1) v = -0.25f * GE[(P1 + q) * P2 + (p - P1)];
      else        v = 0.25f * GE[(p - P1) * P2 + (q - P1)];
    }
    M0b[idx] = bf16r(v);
  } else {
    int idx = (bx - 576) * 256 + t;
    int b = idx / (DIN * 48);
    int rem = idx - b * DIN * 48;
    int d = rem / 48, g = rem - d * 48;
    int q0 = g * 8;
    const float* src = E + (size_t)d * P2 + q0;
    const float* cpb = cp + b * K_;
    short8 o;
#pragma unroll
    for (int e = 0; e < 8; ++e) {
      int q = q0 + e;
      int kidx = (q % P1) / RANK_;
      o[e] = bf16r(src[e] * cpb[kidx]);
    }
    *(short8*)(Ecb + ((size_t)b * DIN + d) * P2 + q0) = o;
  }
}

// ---------------- generic batched bf16 MFMA NT kernel: C = A @ B^T (bf16 out) ----------------
template<int MSZ, int NSZ, int KD>
__global__ __launch_bounds__(256) void k_mf_nt16(const short* __restrict__ A,
                                                 const short* __restrict__ B,
                                                 short* __restrict__ C) {
  int b = blockIdx.z;
  const short* Ab = A + (size_t)b * MSZ * KD;
  short* Cb = C + (size_t)b * MSZ * NSZ;
  int c0 = blockIdx.x * 64, r0 = blockIdx.y * 64;
  __shared__ short As[64][40], Bs[64][40];
  int t = threadIdx.x;
  int l = t & 63, wid = t >> 6;
  int wr = wid >> 1, wc = wid & 1;
  int fr = l & 15, fq = l >> 4;
  int row = t >> 2, cg = t & 3;
  f32x4 acc[2][2] = {};
  for (int kt = 0; kt < KD / 32; ++kt) {
    *(short8*)&As[row][cg * 8] = *(const short8*)(Ab + (size_t)(r0 + row) * KD + kt * 32 + cg * 8);
    *(short8*)&Bs[row][cg * 8] = *(const short8*)(B + (size_t)(c0 + row) * KD + kt * 32 + cg * 8);
    __syncthreads();
    short8 af[2], bf[2];
#pragma unroll
    for (int m = 0; m < 2; ++m) af[m] = *(const short8*)&As[wr * 32 + m * 16 + fr][fq * 8];
#pragma unroll
    for (int n = 0; n < 2; ++n) bf[n] = *(const short8*)&Bs[wc * 32 + n * 16 + fr][fq * 8];
#pragma unroll
    for (int m = 0; m < 2; ++m)
#pragma unroll
      for (int n = 0; n < 2; ++n)
        acc[m][n] = __builtin_amdgcn_mfma_f32_16x16x32_bf16(af[m], bf[n], acc[m][n], 0, 0, 0);
    __syncthreads();
  }
#pragma unroll
  for (int m = 0; m < 2; ++m)
#pragma unroll
    for (int n = 0; n < 2; ++n)
#pragma unroll
      for (int j = 0; j < 4; ++j)
        Cb[(size_t)(r0 + wr * 32 + m * 16 + fq * 4 + j) * NSZ + c0 + wc * 32 + n * 16 + fr] =
            bf16r(acc[m][n][j]);
}

// ---------------- k_mf_G: G = I + Hb @ Ecb^T (f32 out, both batched) ----------------
__global__ __launch_bounds__(256) void k_mf_G(const short* __restrict__ H,
                                              const short* __restrict__ Ec,
                                              float* __restrict__ G) {
  int b = blockIdx.z;
  const short* Ab = H + (size_t)b * DIN * P2;
  const short* Bb = Ec + (size_t)b * DIN * P2;
  float* Gb = G + (size_t)b * DIN * DIN;
  int c0 = blockIdx.x * 64, r0 = blockIdx.y * 64;
  __shared__ short As[64][40], Bs[64][40];
  int t = threadIdx.x;
  int l = t & 63, wid = t >> 6;
  int wr = wid >> 1, wc = wid & 1;
  int fr = l & 15, fq = l >> 4;
  int row = t >> 2, cg = t & 3;
  f32x4 acc[2][2] = {};
  for (int kt = 0; kt < P2 / 32; ++kt) {
    *(short8*)&As[row][cg * 8] = *(const short8*)(Ab + (size_t)(r0 + row) * P2 + kt * 32 + cg * 8);
    *(short8*)&Bs[row][cg * 8] = *(const short8*)(Bb + (size_t)(c0 + row) * P2 + kt * 32 + cg * 8);
    __syncthreads();
    short8 af[2], bf[2];
#pragma unroll
    for (int m = 0; m < 2; ++m) af[m] = *(const short8*)&As[wr * 32 + m * 16 + fr][fq * 8];
#pragma unroll
    for (int n = 0; n < 2; ++n) bf[n] = *(const short8*)&Bs[wc * 32 + n * 16 + fr][fq * 8];
#pragma unroll
    for (int m = 0; m < 2; ++m)
#pragma unroll
      for (int n = 0; n < 2; ++n)
        acc[m][n] = __builtin_amdgcn_mfma_f32_16x16x32_bf16(af[m], bf[n], acc[m][n], 0, 0, 0);
    __syncthreads();
  }
#pragma unroll
  for (int m = 0; m < 2; ++m)
#pragma unroll
    for (int n = 0; n < 2; ++n)
#pragma unroll
      for (int j = 0; j < 4; ++j) {
        int gr = r0 + wr * 32 + m * 16 + fq * 4 + j;
        int gc = c0 + wc * 32 + n * 16 + fr;
        Gb[(size_t)gr * DIN + gc] = acc[m][n][j] + (gr == gc ? 1.0f : 0.0f);
      }
}

// ---------------- k_chol_dp2: panel step + bf16 side-channel for trif ----------------
__global__ __launch_bounds__(64) void k_chol_dp2(float* __restrict__ G, short* __restrict__ Rb,
                                                 short* __restrict__ Wdb, int j0) {
  int b = blockIdx.y;
  int role = blockIdx.x;
  float* Gb = G + (size_t)b * DIN * DIN;
  short* Rbb = Rb + (size_t)b * DIN * DIN;
  __shared__ float D[64][65];
  __shared__ float Wls[64][65];
  __shared__ float dinvs[64];
  int t = threadIdx.x;
#pragma unroll 8
  for (int i = 0; i < 64; ++i) D[i][t] = Gb[(size_t)(j0 + i) * DIN + j0 + t];
  __syncthreads();
  {
    float col[64];
#pragma unroll
    for (int i = 0; i < 64; ++i) col[i] = D[i][t];
#pragma unroll
    for (int j = 0; j < 64; ++j) {
      float djj = __shfl(col[j], j);
      float rjj = sqrtf(fmaxf(djj, 1e-30f));
      float rinv = 1.0f / rjj;
      if (t == j) col[j] = rjj;
      else if (t > j) col[j] *= rinv;
      float djt = col[j];
#pragma unroll
      for (int i = j + 1; i < 64; ++i) {
        float rji = __shfl(col[j], i);
        if (i <= t) col[i] = fmaf(-rji, djt, col[i]);
      }
    }
#pragma unroll
    for (int i = 0; i < 64; ++i) D[i][t] = (i <= t) ? col[i] : 0.0f;
    dinvs[t] = 1.0f / col[t];
  }
  __syncthreads();
  if (role == 0) {
#pragma unroll 4
    for (int i = 0; i < 64; ++i) Wls[i][t] = 0.0f;
    Wls[t][t] = dinvs[t];
    for (int i = 62; i >= 0; --i) {
      float s = 0.0f;
      for (int j = i + 1; j < 64; ++j) s = fmaf(D[i][j], Wls[j][t], s);
      if (t > i) Wls[i][t] = -s * dinvs[i];
    }
    short* Wp = Wdb + ((size_t)b * 8 + (j0 >> 6)) * 4096;
#pragma unroll 4
    for (int i = 0; i < 64; ++i) Wp[i * 64 + t] = bf16r(Wls[i][t]);
  } else {
    int c = j0 + 64 + (role - 1) * 64 + t;
    float a[64];
#pragma unroll
    for (int i = 0; i < 64; ++i) a[i] = Gb[(size_t)(j0 + i) * DIN + c];
#pragma unroll
    for (int j = 0; j < 64; ++j) {
      float aj = a[j] * dinvs[j];
      a[j] = aj;
#pragma unroll
      for (int i = j + 1; i < 64; ++i) a[i] = fmaf(-D[j][i], aj, a[i]);
    }
#pragma unroll
    for (int i = 0; i < 64; ++i) {
      Gb[(size_t)(j0 + i) * DIN + c] = a[i];
      Rbb[(size_t)(j0 + i) * DIN + c] = bf16r(a[i]);
    }
  }
}

// ---------------- k_chol_tr: trailing update C -= P^T P over 64x64 tile pairs ----------------
__global__ __launch_bounds__(256) void k_chol_tr(float* __restrict__ G, int j0, int nt) {
  int b = blockIdx.y;
  int pi = blockIdx.x;
  int ti = 0, accum = 0;
  while (pi >= accum + (nt - ti)) { accum += nt - ti; ++ti; }
  int tc = ti + (pi - accum);
  float* Gb = G + (size_t)b * DIN * DIN;
  __shared__ float As[64][65], Bs[64][65];
  int t = threadIdx.x;
  int ibase = j0 + 64 + ti * 64, cbase = j0 + 64 + tc * 64;
  for (int idx = t; idx < 4096; idx += 256) {
    int j = idx >> 6, c = idx & 63;
    As[j][c] = Gb[(size_t)(j0 + j) * DIN + ibase + c];
    Bs[j][c] = Gb[(size_t)(j0 + j) * DIN + cbase + c];
  }
  __syncthreads();
  int tx = t & 15, ty = t >> 4;
  float acc[4][4] = {};
#pragma unroll 8
  for (int k = 0; k < 64; ++k) {
    float a[4], bv[4];
#pragma unroll
    for (int u = 0; u < 4; ++u) a[u] = As[k][ty * 4 + u];
#pragma unroll
    for (int v = 0; v < 4; ++v) bv[v] = Bs[k][tx * 4 + v];
#pragma unroll
    for (int u = 0; u < 4; ++u)
#pragma unroll
      for (int v = 0; v < 4; ++v) acc[u][v] = fmaf(a[u], bv[v], acc[u][v]);
  }
#pragma unroll
  for (int u = 0; u < 4; ++u) {
    size_t ro = (size_t)(ibase + ty * 4 + u) * DIN + cbase + tx * 4;
#pragma unroll
    for (int v = 0; v < 4; ++v) Gb[ro + v] -= acc[u][v];
  }
}

// ---------------- k_trif: fused trisolve (bf16 R/Wd operands, XCD-chunked blocks) ----------------
__global__ __launch_bounds__(256) void k_trif(const float* __restrict__ x, const short* __restrict__ Rb,
                                              const short* __restrict__ Wdb, short* __restrict__ ybf,
                                              short* __restrict__ ycb) {
  int wg = blockIdx.x;
  int swz = (wg & 7) * 64 + (wg >> 3);  // XCD-chunked bijective (512 % 8 == 0)
  int b = swz >> 4;
  int n0 = (swz & 15) * 16;
  const short* Rbb = Rb + (size_t)b * DIN * DIN;
  const float* xb = x + ((size_t)b * N_ + n0) * DIN;
  __shared__ float Yl[16][517];
  __shared__ float Rs[64][65];
  __shared__ float Wds[64][65];
  __shared__ float Ytmp[16][69];
  int t = threadIdx.x;
  for (int idx = t; idx < 16 * DIN; idx += 256)
    Yl[idx >> 9][idx & 511] = xb[(size_t)(idx >> 9) * DIN + (idx & 511)];
  __syncthreads();
  int r = t & 15, cg = t >> 4;
  for (int p = 7; p >= 0; --p) {
    int j0 = p * 64;
    int kN = DIN - j0 - 64;
    float acc[4] = {0.f, 0.f, 0.f, 0.f};
    for (int kb = 0; kb < kN; kb += 64) {
      for (int idx = t; idx < 4096; idx += 256) {
        int kk = idx & 63, c = idx >> 6;
        Rs[kk][c] = b16f(Rbb[(size_t)(j0 + c) * DIN + j0 + 64 + kb + kk]);
      }
      __syncthreads();
#pragma unroll 8
      for (int kk = 0; kk < 64; ++kk) {
        float a = Yl[r][j0 + 64 + kb + kk];
#pragma unroll
        for (int v = 0; v < 4; ++v) acc[v] = fmaf(a, Rs[kk][cg * 4 + v], acc[v]);
      }
      __syncthreads();
    }
#pragma unroll
    for (int v = 0; v < 4; ++v) Ytmp[r][cg * 4 + v] = Yl[r][j0 + cg * 4 + v] - acc[v];
    const short* Wp = Wdb + ((size_t)b * 8 + p) * 4096;
    for (int idx = t; idx < 4096; idx += 256) Wds[idx >> 6][idx & 63] = b16f(Wp[idx]);
    __syncthreads();
    float o[4] = {0.f, 0.f, 0.f, 0.f};
#pragma unroll 8
    for (int jj = 0; jj < 64; ++jj) {
      float a = Ytmp[r][jj];
#pragma unroll
      for (int v = 0; v < 4; ++v) o[v] = fmaf(a, Wds[cg * 4 + v][jj], o[v]);
    }
    __syncthreads();
#pragma unroll
    for (int v = 0; v < 4; ++v) Yl[r][j0 + cg * 4 + v] = o[v];
    __syncthreads();
  }
  for (int idx = t; idx < 16 * DIN; idx += 256) {
    int rr = idx >> 9, c = idx & 511;
    float yv = Yl[rr][c];
    float xv = xb[(size_t)rr * DIN + c];
    size_t gi = ((size_t)b * N_ + n0 + rr) * DIN + c;
    ybf[gi] = bf16r(yv);
    ycb[gi] = bf16r(yv - xv);
  }
}

// ---------------- k_yEuv: yE = y @ E (MFMA) with fused vb epilogue ----------------
__global__ __launch_bounds__(256) void k_yEuv(const short* __restrict__ A,
                                              const short* __restrict__ B,
                                              const float* __restrict__ cp,
                                              const float* __restrict__ gate,
                                              short* __restrict__ C, short* __restrict__ vb) {
  int b = blockIdx.z;
  const short* Ab = A + (size_t)b * N_ * DIN;
  short* Cb = C + (size_t)b * N_ * P2;
  int c0 = blockIdx.x * 64, r0 = blockIdx.y * 64;
  __shared__ short As[64][40], Bs[64][40];
  __shared__ float cps[K_];
  int t = threadIdx.x;
  if (t < K_) cps[t] = cp[b * K_ + t];
  int l = t & 63, wid = t >> 6;
  int wr = wid >> 1, wc = wid & 1;
  int fr = l & 15, fq = l >> 4;
  int row = t >> 2, cg = t & 3;
  f32x4 acc[2][2] = {};
  __syncthreads();
  for (int kt = 0; kt < DIN / 32; ++kt) {
    *(short8*)&As[row][cg * 8] = *(const short8*)(Ab + (size_t)(r0 + row) * DIN + kt * 32 + cg * 8);
    *(short8*)&Bs[row][cg * 8] = *(const short8*)(B + (size_t)(c0 + row) * DIN + kt * 32 + cg * 8);
    __syncthreads();
    short8 af[2], bf[2];
#pragma unroll
    for (int m = 0; m < 2; ++m) af[m] = *(const short8*)&As[wr * 32 + m * 16 + fr][fq * 8];
#pragma unroll
    for (int n = 0; n < 2; ++n) bf[n] = *(const short8*)&Bs[wc * 32 + n * 16 + fr][fq * 8];
#pragma unroll
    for (int m = 0; m < 2; ++m)
#pragma unroll
      for (int n = 0; n < 2; ++n)
        acc[m][n] = __builtin_amdgcn_mfma_f32_16x16x32_bf16(af[m], bf[n], acc[m][n], 0, 0, 0);
    __syncthreads();
  }
  float gt = gate[b];
#pragma unroll
  for (int m = 0; m < 2; ++m)
#pragma unroll
    for (int n = 0; n < 2; ++n)
#pragma unroll
      for (int j = 0; j < 4; ++j) {
        int gr = r0 + wr * 32 + m * 16 + fq * 4 + j;
        int gc = c0 + wc * 32 + n * 16 + fr;
        float v = acc[m][n][j];
        Cb[(size_t)gr * P2 + gc] = bf16r(v);
        if (gc < P1)
          vb[((size_t)b * N_ + gr) * P1 + gc] = bf16r(gt * cps[gc / RANK_] * v);
      }
}

// ---------------- k_mf_w: wb = bf16(gate*(yc - u @ E^T)) ----------------
__global__ __launch_bounds__(256) void k_mf_w(const short* __restrict__ yE16,
                                              const short* __restrict__ Eb,
                                              const short* __restrict__ ycb,
                                              const float* __restrict__ cp,
                                              const float* __restrict__ gate,
                                              short* __restrict__ wb) {
  int b = blockIdx.z;
  const short* yEb = yE16 + (size_t)b * N_ * P2;
  int c0 = blockIdx.x * 64, r0 = blockIdx.y * 64;
  __shared__ short As[64][40], Bs[64][40];
  __shared__ float cps[K_];
  int t = threadIdx.x;
  if (t < K_) cps[t] = 0.5f * cp[b * K_ + t];
  int l = t & 63, wid = t >> 6;
  int wr = wid >> 1, wc = wid & 1;
  int fr = l & 15, fq = l >> 4;
  int row = t >> 2, cg = t & 3;
  f32x4 acc[2][2] = {};
  __syncthreads();
  for (int kt = 0; kt < P2 / 32; ++kt) {
    int ksrc0 = (kt * 32 + P1) % P2;
    short8 raw = *(const short8*)(yEb + (size_t)(r0 + row) * P2 + ksrc0 + cg * 8);
    short8 oa;
#pragma unroll
    for (int e = 0; e < 8; ++e) {
      int q = kt * 32 + cg * 8 + e;
      int kidx = (q % P1) / RANK_;
      oa[e] = bf16r(b16f(raw[e]) * cps[kidx]);
    }
    *(short8*)&As[row][cg * 8] = oa;
    *(short8*)&Bs[row][cg * 8] = *(const short8*)(Eb + (size_t)(c0 + row) * P2 + kt * 32 + cg * 8);
    __syncthreads();
    short8 af[2], bf[2];
#pragma unroll
    for (int m = 0; m < 2; ++m) af[m] = *(const short8*)&As[wr * 32 + m * 16 + fr][fq * 8];
#pragma unroll
    for (int n = 0; n < 2; ++n) bf[n] = *(const short8*)&Bs[wc * 32 + n * 16 + fr][fq * 8];
#pragma unroll
    for (int m = 0; m < 2; ++m)
#pragma unroll
      for (int n = 0; n < 2; ++n)
        acc[m][n] = __builtin_amdgcn_mfma_f32_16x16x32_bf16(af[m], bf[n], acc[m][n], 0, 0, 0);
    __syncthreads();
  }
  float gt = gate[b];
#pragma unroll
  for (int m = 0; m < 2; ++m)
#pragma unroll
    for (int n = 0; n < 2; ++n)
#pragma unroll
      for (int j = 0; j < 4; ++j) {
        int gr = r0 + wr * 32 + m * 16 + fq * 4 + j;
        int gc = c0 + wc * 32 + n * 16 + fr;
        size_t gi = ((size_t)b * N_ + gr) * DIN + gc;
        wb[gi] = bf16r(gt * (b16f(ycb[gi]) - acc[m][n][j]));
      }
}

// ---------------- K13: MFMA fused output GEMM: out = [x|w|v] @ Bcat^T + bias ----------------
__device__ inline short8 loadA8(const float* __restrict__ x, const short* __restrict__ wb,
                                const short* __restrict__ vb, int grow, int k0) {
  if (k0 < 512) {
    const float* p = x + (size_t)grow * 512 + k0;
    float4 f0 = *(const float4*)p;
    float4 f1 = *(const float4*)(p + 4);
    short8 o;
    o[0] = bf16r(f0.x); o[1] = bf16r(f0.y); o[2] = bf16r(f0.z); o[3] = bf16r(f0.w);
    o[4] = bf16r(f1.x); o[5] = bf16r(f1.y); o[6] = bf16r(f1.z); o[7] = bf16r(f1.w);
    return o;
  } else if (k0 < 1024) {
    return *(const short8*)(wb + (size_t)grow * 512 + k0 - 512);
  } else {
    return *(const short8*)(vb + (size_t)grow * 192 + k0 - 1024);
  }
}

__global__ __launch_bounds__(256) void k_final(
    const float* __restrict__ x, const short* __restrict__ wb, const short* __restrict__ vb,
    const short* __restrict__ Bcat, const float* __restrict__ bias, float* __restrict__ out) {
  __shared__ short As[2][4096];
  __shared__ short Bs[2][4096];
  int t = threadIdx.x;
  int c0 = blockIdx.x * 128;
  int r0 = blockIdx.y * 128;
  int l = t & 63, wid = t >> 6;
  int wr = wid >> 1, wc = wid & 1;
  int fr = l & 15, fq = l >> 4;
  f32x4 acc[4][4] = {};
  short8 ra0, ra1, rb0, rb1;
  const int row0 = t >> 2, c8 = t & 3;
  const int row1 = row0 + 64;
  ra0 = loadA8(x, wb, vb, r0 + row0, c8 * 8);
  ra1 = loadA8(x, wb, vb, r0 + row1, c8 * 8);
  rb0 = *(const short8*)(Bcat + (size_t)(c0 + row0) * 1216 + c8 * 8);
  rb1 = *(const short8*)(Bcat + (size_t)(c0 + row1) * 1216 + c8 * 8);
  *(short8*)&As[0][row0 * 32 + c8 * 8] = ra0;
  *(short8*)&As[0][row1 * 32 + c8 * 8] = ra1;
  *(short8*)&Bs[0][row0 * 32 + c8 * 8] = rb0;
  *(short8*)&Bs[0][row1 * 32 + c8 * 8] = rb1;
  __syncthreads();
  for (int kt = 0; kt < 38; ++kt) {
    int cur = kt & 1;
    if (kt + 1 < 38) {
      int k0 = (kt + 1) * 32;
      ra0 = loadA8(x, wb, vb, r0 + row0, k0 + c8 * 8);
      ra1 = loadA8(x, wb, vb, r0 + row1, k0 + c8 * 8);
      rb0 = *(const short8*)(Bcat + (size_t)(c0 + row0) * 1216 + k0 + c8 * 8);
      rb1 = *(const short8*)(Bcat + (size_t)(c0 + row1) * 1216 + k0 + c8 * 8);
    }
    short8 af[4], bf[4];
#pragma unroll
    for (int m = 0; m < 4; ++m)
      af[m] = *(const short8*)&As[cur][(wr * 64 + m * 16 + fr) * 32 + fq * 8];
#pragma unroll
    for (int n = 0; n < 4; ++n)
      bf[n] = *(const short8*)&Bs[cur][(wc * 64 + n * 16 + fr) * 32 + fq * 8];
#pragma unroll
    for (int m = 0; m < 4; ++m)
#pragma unroll
      for (int n = 0; n < 4; ++n)
        acc[m][n] = __builtin_amdgcn_mfma_f32_16x16x32_bf16(af[m], bf[n], acc[m][n], 0, 0, 0);
    __syncthreads();
    if (kt + 1 < 38) {
      int nxt = cur ^ 1;
      *(short8*)&As[nxt][row0 * 32 + c8 * 8] = ra0;
      *(short8*)&As[nxt][row1 * 32 + c8 * 8] = ra1;
      *(short8*)&Bs[nxt][row0 * 32 + c8 * 8] = rb0;
      *(short8*)&Bs[nxt][row1 * 32 + c8 * 8] = rb1;
    }
    __syncthreads();
  }
#pragma unroll
  for (int n = 0; n < 4; ++n) {
    int col = c0 + wc * 64 + n * 16 + fr;
    float bv = bias[col];
#pragma unroll
    for (int m = 0; m < 4; ++m) {
      int rbase = r0 + wr * 64 + m * 16 + fq * 4;
#pragma unroll
      for (int j = 0; j < 4; ++j)
        out[(size_t)(rbase + j) * DOUT + col] = acc[m][n][j] + bv;
    }
  }
}

extern "C" void kernel_launch(void* const* d_in, const int* in_sizes, int n_in,
                              void* d_out, int out_size, void* d_ws, size_t ws_size,
                              hipStream_t stream) {
  (void)in_sizes; (void)n_in; (void)out_size; (void)ws_size;
  const float* x     = (const float*)d_in[0];
  const float* Wsh   = (const float*)d_in[1];
  const float* bias  = (const float*)d_in[2];
  const float* U0    = (const float*)d_in[3];
  const float* leftb = (const float*)d_in[4];
  const float* rightb= (const float*)d_in[5];
  const float* W1    = (const float*)d_in[6];
  const float* b1    = (const float*)d_in[7];
  const float* Wc    = (const float*)d_in[8];
  const float* bc    = (const float*)d_in[9];
  const float* Wg    = (const float*)d_in[10];
  const float* bg    = (const float*)d_in[11];
  float* out = (float*)d_out;

  float* wsf = (float*)d_ws;
  float* hgel  = wsf + 0;
  float* gate  = wsf + 49664;
  float* cp    = wsf + 49792;
  float* LcatF = wsf + 50304;
  float* E     = wsf + 443520;
  float* GLL   = wsf + 640128;
  float* GE    = wsf + 676992;
  short* M0b16 = (short*)(wsf + 824448);
  short* Eb16  = (short*)(wsf + 898176);
  short* Etb16 = (short*)(wsf + 996480);
  short* wb    = (short*)(wsf + 1094784);
  short* Ecb   = (short*)(wsf + 3191936);
  short* ybf   = (short*)(wsf + 3191936);
  short* vb    = (short*)(wsf + 5289088);
  short* Hb16  = (short*)(wsf + 6337664);
  short* ycb   = (short*)(wsf + 6337664);
  short* Bcat  = (short*)(wsf + 9483392);
  float* sp      = wsf + 10728576;
  float* s2p     = wsf + 10859648;
  float* Ppart   = wsf + 10990720;
  float* GLLpart = wsf + 11383936;
  // d_out layout (floats): G [0,8388608) | Rb16 [8388608,12582912) | yE16 [12582912,14155776)
  //                        | Wdb16 [14155776,14680064) — all dead before k_final overwrites
  float* G = out;
  short* Rb16 = (short*)(out + 8388608);
  short* yE16 = (short*)(out + 12582912);
  short* Wdb16 = (short*)(out + 14155776);

  k_pre1<<<256 + 1920, 256, 0, stream>>>(x, leftb, rightb, sp, s2p, LcatF, E);
  k_pre2<<<624, 256, 0, stream>>>(x, sp, s2p, W1, b1, U0, LcatF, hgel, Ppart, GLLpart);
  k_pre2b<<<528, 256, 0, stream>>>(Ppart, GLLpart, E, GLL);
  k_pre3<<<2128, 256, 0, stream>>>(E, Wsh, U0, LcatF, GE, Bcat, Eb16, Etb16);
  k_pre4<<<1, 512, 0, stream>>>(GLL, GE, hgel, Wc, bc, Wg, bg, gate, cp);
  k_pre5<<<3648, 256, 0, stream>>>(GLL, GE, E, cp, M0b16, Ecb);
  k_mf_nt16<DIN, P2, P2><<<dim3(P2 / 64, DIN / 64, B_), 256, 0, stream>>>(Ecb, M0b16, Hb16);
  k_mf_G<<<dim3(DIN / 64, DIN / 64, B_), 256, 0, stream>>>(Hb16, Ecb, G);
  // right-looking blocked Cholesky (round-12/14 proven): 8 dp + 7 tr launches
  for (int p = 0; p < 8; ++p) {
    int j0 = p * 64;
    int nt = 7 - p;
    k_chol_dp2<<<dim3(nt + 1, B_), 64, 0, stream>>>(G, Rb16, Wdb16, j0);
    if (nt > 0)
      k_chol_tr<<<dim3(nt * (nt + 1) / 2, B_), 256, 0, stream>>>(G, j0, nt);
  }
  k_trif<<<512, 256, 0, stream>>>(x, Rb16, Wdb16, ybf, ycb);
  k_yEuv<<<dim3(P2 / 64, N_ / 64, B_), 256, 0, stream>>>(ybf, Etb16, cp, gate, yE16, vb);
  k_mf_w<<<dim3(DIN / 64, N_ / 64, B_), 256, 0, stream>>>(yE16, Eb16, ycb, cp, gate, wb);
  k_final<<<dim3(DOUT / 128, (B_ * N_) / 128), 256, 0, stream>>>(x, wb, vb, Bcat, bias, out);
}